// Round 1
// baseline (8342.446 us; speedup 1.0000x reference)
//
#include <hip/hip_runtime.h>
#include <math.h>

// ---------------- problem constants ----------------
constexpr int TT = 256, BB = 16, DD = 512, HRr = 256;
constexpr int NTOK = 4096;                 // T*B
constexpr int RTOT = 3456;                 // 768 + 384 + 768 + 1536
constexpr int ROFF = 0, E1OFF = 768, E2OFF = 1152, E3OFF = 1920;
constexpr int H1 = 128, H2 = 256, H3 = 512;

// ---------------- workspace layout (bytes) ----------------
constexpr size_t OFF_TSUM = 0;                                   // 4 f
constexpr size_t OFF_TCNT = 16;                                  // 4 f
constexpr size_t OFF_HBR  = 32;                                  // 2*4096 ull
constexpr size_t OFF_HB3  = OFF_HBR + 2ull*4096*8;               // 2*512 ull
constexpr size_t OFF_HB2  = OFF_HB3 + 2ull*512*8;                // 2*256 ull
constexpr size_t OFF_HB1  = OFF_HB2 + 2ull*256*8;                // 2*128 ull
constexpr size_t ZBYTES   = OFF_HB1 + 2ull*128*8;                // = 79904
constexpr size_t OFF_GI   = 81920;
constexpr size_t OFF_HS   = OFF_GI  + (size_t)NTOK*RTOT*4;
constexpr size_t OFF_HA3  = OFF_HS  + (size_t)NTOK*256*4;
constexpr size_t OFF_HA2  = OFF_HA3 + (size_t)NTOK*512*4;
constexpr size_t OFF_HA1  = OFF_HA2 + (size_t)NTOK*256*4;
constexpr size_t OFF_AP   = OFF_HA1 + (size_t)NTOK*128*4;
constexpr size_t OFF_MU   = OFF_AP  + (size_t)NTOK*896*4;
constexpr size_t OFF_RSTD = OFF_MU  + 896*4;

typedef unsigned long long ull;

__device__ __forceinline__ ull agload(const ull* p) {
  return __hip_atomic_load(p, __ATOMIC_RELAXED, __HIP_MEMORY_SCOPE_AGENT);
}
__device__ __forceinline__ void agstore(ull* p, ull v) {
  __hip_atomic_store(p, v, __ATOMIC_RELAXED, __HIP_MEMORY_SCOPE_AGENT);
}
__device__ __forceinline__ float lowf(ull v) { return __uint_as_float((unsigned)(v & 0xffffffffu)); }
__device__ __forceinline__ unsigned tagof(ull v) { return (unsigned)(v >> 32); }
__device__ __forceinline__ ull packh(int tag, float v) {
  return ((ull)(unsigned)tag << 32) | (ull)__float_as_uint(v);
}

// ================= phase 1: gi = x @ Wih^T + b_ih (all 3456 rows) =================
__global__ __launch_bounds__(256) void gemm1_kernel(
    const float* __restrict__ X,
    const float* __restrict__ wR, const float* __restrict__ w1,
    const float* __restrict__ w2, const float* __restrict__ w3,
    const float* __restrict__ bR, const float* __restrict__ b1,
    const float* __restrict__ b2, const float* __restrict__ b3,
    float* __restrict__ GI)
{
  __shared__ float At[32*64];
  __shared__ float Bt[32*64];
  const int n0 = blockIdx.x * 64;
  const int r0 = blockIdx.y * 64;
  const float* W; const float* bias; int rs;
  if (r0 < 768)       { W = wR; bias = bR; rs = 0; }
  else if (r0 < 1152) { W = w1; bias = b1; rs = 768; }
  else if (r0 < 1920) { W = w2; bias = b2; rs = 1152; }
  else                { W = w3; bias = b3; rs = 1920; }
  const int lr0 = r0 - rs;
  const int tid = threadIdx.x;
  const int lm = tid & 63, lk4 = tid >> 6;
  const int tx = tid & 15, ty = tid >> 4;
  float acc[4][4];
#pragma unroll
  for (int i = 0; i < 4; ++i)
#pragma unroll
    for (int q = 0; q < 4; ++q) acc[i][q] = 0.f;

  for (int kb = 0; kb < 512; kb += 32) {
    const float4 a0 = *(const float4*)(X + (size_t)(n0+lm)*512 + kb + lk4*8);
    const float4 a1 = *(const float4*)(X + (size_t)(n0+lm)*512 + kb + lk4*8 + 4);
    const float4 c0 = *(const float4*)(W + (size_t)(lr0+lm)*512 + kb + lk4*8);
    const float4 c1 = *(const float4*)(W + (size_t)(lr0+lm)*512 + kb + lk4*8 + 4);
    __syncthreads();
    At[(lk4*8+0)*64+lm]=a0.x; At[(lk4*8+1)*64+lm]=a0.y; At[(lk4*8+2)*64+lm]=a0.z; At[(lk4*8+3)*64+lm]=a0.w;
    At[(lk4*8+4)*64+lm]=a1.x; At[(lk4*8+5)*64+lm]=a1.y; At[(lk4*8+6)*64+lm]=a1.z; At[(lk4*8+7)*64+lm]=a1.w;
    Bt[(lk4*8+0)*64+lm]=c0.x; Bt[(lk4*8+1)*64+lm]=c0.y; Bt[(lk4*8+2)*64+lm]=c0.z; Bt[(lk4*8+3)*64+lm]=c0.w;
    Bt[(lk4*8+4)*64+lm]=c1.x; Bt[(lk4*8+5)*64+lm]=c1.y; Bt[(lk4*8+6)*64+lm]=c1.z; Bt[(lk4*8+7)*64+lm]=c1.w;
    __syncthreads();
#pragma unroll
    for (int k = 0; k < 32; ++k) {
      const float4 av = *(const float4*)&At[k*64 + ty*4];
      const float4 bv = *(const float4*)&Bt[k*64 + tx*4];
      acc[0][0]=fmaf(av.x,bv.x,acc[0][0]); acc[0][1]=fmaf(av.x,bv.y,acc[0][1]); acc[0][2]=fmaf(av.x,bv.z,acc[0][2]); acc[0][3]=fmaf(av.x,bv.w,acc[0][3]);
      acc[1][0]=fmaf(av.y,bv.x,acc[1][0]); acc[1][1]=fmaf(av.y,bv.y,acc[1][1]); acc[1][2]=fmaf(av.y,bv.z,acc[1][2]); acc[1][3]=fmaf(av.y,bv.w,acc[1][3]);
      acc[2][0]=fmaf(av.z,bv.x,acc[2][0]); acc[2][1]=fmaf(av.z,bv.y,acc[2][1]); acc[2][2]=fmaf(av.z,bv.z,acc[2][2]); acc[2][3]=fmaf(av.z,bv.w,acc[2][3]);
      acc[3][0]=fmaf(av.w,bv.x,acc[3][0]); acc[3][1]=fmaf(av.w,bv.y,acc[3][1]); acc[3][2]=fmaf(av.w,bv.z,acc[3][2]); acc[3][3]=fmaf(av.w,bv.w,acc[3][3]);
    }
  }
  const float4 bb = *(const float4*)(bias + lr0 + tx*4);
#pragma unroll
  for (int i = 0; i < 4; ++i) {
    float4 o;
    o.x = acc[i][0] + bb.x; o.y = acc[i][1] + bb.y; o.z = acc[i][2] + bb.z; o.w = acc[i][3] + bb.w;
    *(float4*)(GI + (size_t)(n0+ty*4+i)*RTOT + r0 + tx*4) = o;
  }
}

// ================= phase 2: persistent scans =================
struct ScanArgs {
  const float* GI;
  const float* rwhh; const float* rbhh; ull* hbR; float* hs;
  const float* w1; const float* b1; ull* hb1; float* ha1;
  const float* w2; const float* b2; ull* hb2; float* ha2;
  const float* w3; const float* b3; ull* hb3; float* ha3;
};

// expert scan: C = H/32 workgroups of 256 threads; thread = (j in [0,32), kc in [0,8))
template<int H, int CF4>
__device__ void expert_scan(const float* __restrict__ GIe, const float* __restrict__ whh,
                            const float* __restrict__ bhh, ull* __restrict__ hb,
                            float* __restrict__ hall, float* __restrict__ hsm, int wg)
{
  const int tid = threadIdx.x;
  const int j = tid >> 3, kc = tid & 7;
  const int jg = wg * 32 + j;
  constexpr int CH = CF4 * 4;  // k-chunk per thread = H/8
  float4 wr[CF4], wz[CF4], wn[CF4];
#pragma unroll
  for (int i4 = 0; i4 < CF4; ++i4) {
    const int kk = kc * CH + ((i4 + kc) & (CF4 - 1)) * 4;   // bank-rotated storage
    wr[i4] = *(const float4*)(whh + (size_t)jg * H + kk);
    wz[i4] = *(const float4*)(whh + (size_t)(H + jg) * H + kk);
    wn[i4] = *(const float4*)(whh + (size_t)(2*H + jg) * H + kk);
  }
  float gbr = 0.f, gbz = 0.f, gbn = 0.f, gr = 0.f, gz = 0.f, gn = 0.f;
  if (kc == 0) {
    gbr = bhh[jg]; gbz = bhh[H + jg]; gbn = bhh[2*H + jg];
    gr = GIe[jg]; gz = GIe[H + jg]; gn = GIe[2*H + jg];   // token 0
  }
  constexpr bool A1 = (H > 256);
  for (int t = 0; t < NTOK; ++t) {
    ull* buf = hb + (size_t)(t & 1) * H;
    // --- poll h_t (tag==t), both loads in flight ---
    const bool a0 = (tid < H);
    ull v0 = 0, v1 = 0;
    if (a0) v0 = agload(buf + tid);
    if (A1) v1 = agload(buf + tid + 256);
    while ((a0 && tagof(v0) != (unsigned)t) || (A1 && tagof(v1) != (unsigned)t)) {
      if (a0 && tagof(v0) != (unsigned)t) v0 = agload(buf + tid);
      if (A1 && tagof(v1) != (unsigned)t) v1 = agload(buf + tid + 256);
    }
    if (a0) hsm[tid] = lowf(v0);
    if (A1) hsm[tid + 256] = lowf(v1);
    __syncthreads();
    // --- prefetch next-step gi (hidden under matvec) ---
    float ngr = 0.f, ngz = 0.f, ngn = 0.f;
    if (kc == 0 && t + 1 < NTOK) {
      const float* g = GIe + (size_t)(t + 1) * RTOT;
      ngr = g[jg]; ngz = g[H + jg]; ngn = g[2*H + jg];
    }
    // --- matvec partials (weights in regs, h from LDS, bank-rotated) ---
    float pr = 0.f, pz = 0.f, pn = 0.f;
    const float4* hv = (const float4*)hsm + kc * CF4;
#pragma unroll
    for (int i4 = 0; i4 < CF4; ++i4) {
      const float4 h4 = hv[(i4 + kc) & (CF4 - 1)];
      pr = fmaf(wr[i4].x, h4.x, pr); pr = fmaf(wr[i4].y, h4.y, pr);
      pr = fmaf(wr[i4].z, h4.z, pr); pr = fmaf(wr[i4].w, h4.w, pr);
      pz = fmaf(wz[i4].x, h4.x, pz); pz = fmaf(wz[i4].y, h4.y, pz);
      pz = fmaf(wz[i4].z, h4.z, pz); pz = fmaf(wz[i4].w, h4.w, pz);
      pn = fmaf(wn[i4].x, h4.x, pn); pn = fmaf(wn[i4].y, h4.y, pn);
      pn = fmaf(wn[i4].z, h4.z, pn); pn = fmaf(wn[i4].w, h4.w, pn);
    }
#pragma unroll
    for (int off = 4; off; off >>= 1) {
      pr += __shfl_down(pr, off); pz += __shfl_down(pz, off); pn += __shfl_down(pn, off);
    }
    if (kc == 0) {
      const float hprev = hsm[jg];
      const float rg = 1.f / (1.f + expf(-(gr + gbr + pr)));
      const float zg = 1.f / (1.f + expf(-(gz + gbz + pz)));
      const float nn = tanhf(gn + rg * (pn + gbn));
      const float hn = (1.f - zg) * nn + zg * hprev;
      agstore(hb + (size_t)((t + 1) & 1) * H + jg, packh(t + 1, hn));
      hall[(size_t)t * H + jg] = hn;
    }
    gr = ngr; gz = ngz; gn = ngn;
    __syncthreads();
  }
}

// router scan: 16 WGs of 256 threads; matvec thread = (j in [0,16), kc in [0,16))
__device__ void router_scan(const float* __restrict__ GI, const float* __restrict__ whh,
                            const float* __restrict__ bhh, ull* __restrict__ hb,
                            float* __restrict__ hs, float* __restrict__ hsm,
                            float* __restrict__ ghsm, int wg)
{
  const int tid = threadIdx.x;
  const int j = tid >> 4, kc = tid & 15;
  const int jg = wg * 16 + j;
  float wr[16], wz[16], wn[16];
#pragma unroll
  for (int i = 0; i < 16; ++i) {
    const int kk = kc * 16 + ((i + kc) & 15);
    wr[i] = whh[(size_t)jg * 256 + kk];
    wz[i] = whh[(size_t)(256 + jg) * 256 + kk];
    wn[i] = whh[(size_t)(512 + jg) * 256 + kk];
  }
  // gate-stage identity: (b2, j2)
  const int j2 = tid & 15, b2 = tid >> 4;
  const int jg2 = wg * 16 + j2;
  const float gbr = bhh[jg2], gbz = bhh[256 + jg2], gbn = bhh[512 + jg2];
  float gr, gz, gn;
  { const float* g = GI + (size_t)b2 * RTOT; gr = g[jg2]; gz = g[256 + jg2]; gn = g[512 + jg2]; }

  for (int t = 0; t < TT; ++t) {
    ull* buf = hb + (size_t)(t & 1) * 4096;
    // poll 16 elems/thread, first-shot issued together
    ull v[16];
#pragma unroll
    for (int q = 0; q < 16; ++q) v[q] = agload(buf + tid + q * 256);
    bool all;
    do {
      all = true;
#pragma unroll
      for (int q = 0; q < 16; ++q) {
        if (tagof(v[q]) != (unsigned)t) { v[q] = agload(buf + tid + q * 256); all = false; }
      }
    } while (!all);
#pragma unroll
    for (int q = 0; q < 16; ++q) hsm[tid + q * 256] = lowf(v[q]);
    __syncthreads();

    float ngr = 0.f, ngz = 0.f, ngn = 0.f;
    if (t + 1 < TT) {
      const float* g = GI + (size_t)((t + 1) * 16 + b2) * RTOT;
      ngr = g[jg2]; ngz = g[256 + jg2]; ngn = g[512 + jg2];
    }
    float ar[16], az[16], an[16];
#pragma unroll
    for (int b = 0; b < 16; ++b) { ar[b] = 0.f; az[b] = 0.f; an[b] = 0.f; }
#pragma unroll
    for (int i = 0; i < 16; ++i) {
      const int kk = kc * 16 + ((i + kc) & 15);
#pragma unroll
      for (int b = 0; b < 16; ++b) {
        const float hvv = hsm[b * 256 + kk];
        ar[b] = fmaf(wr[i], hvv, ar[b]);
        az[b] = fmaf(wz[i], hvv, az[b]);
        an[b] = fmaf(wn[i], hvv, an[b]);
      }
    }
#pragma unroll
    for (int b = 0; b < 16; ++b) {
      for (int off = 8; off; off >>= 1) {
        ar[b] += __shfl_down(ar[b], off);
        az[b] += __shfl_down(az[b], off);
        an[b] += __shfl_down(an[b], off);
      }
    }
    if (kc == 0) {
#pragma unroll
      for (int b = 0; b < 16; ++b) {
        ghsm[(b * 16 + j) * 3 + 0] = ar[b];
        ghsm[(b * 16 + j) * 3 + 1] = az[b];
        ghsm[(b * 16 + j) * 3 + 2] = an[b];
      }
    }
    __syncthreads();
    const float pr = ghsm[(b2 * 16 + j2) * 3 + 0];
    const float pz = ghsm[(b2 * 16 + j2) * 3 + 1];
    const float pn = ghsm[(b2 * 16 + j2) * 3 + 2];
    const float hprev = hsm[b2 * 256 + jg2];
    const float rg = 1.f / (1.f + expf(-(gr + gbr + pr)));
    const float zg = 1.f / (1.f + expf(-(gz + gbz + pz)));
    const float nn = tanhf(gn + rg * (pn + gbn));
    const float hn = (1.f - zg) * nn + zg * hprev;
    agstore(hb + (size_t)((t + 1) & 1) * 4096 + b2 * 256 + jg2, packh(t + 1, hn));
    hs[((size_t)t * 16 + b2) * 256 + jg2] = hn;
    gr = ngr; gz = ngz; gn = ngn;
    __syncthreads();
  }
}

__global__ __launch_bounds__(256, 1) void scan_kernel(ScanArgs A)
{
  __shared__ float sm[4096 + 768];
  const int bid = blockIdx.x;
  const int xcd = bid & 7, slot = bid >> 3;   // hoped round-robin XCD mapping (speed-only)
  if (xcd == 0)                 expert_scan<512,16>(A.GI + E3OFF, A.w3, A.b3, A.hb3, A.ha3, sm, slot);
  else if (xcd == 1)            router_scan(A.GI, A.rwhh, A.rbhh, A.hbR, A.hs, sm, sm + 4096, slot);
  else if (xcd == 2 && slot<8)  expert_scan<256,8>(A.GI + E2OFF, A.w2, A.b2, A.hb2, A.ha2, sm, slot);
  else if (xcd == 3 && slot<4)  expert_scan<128,4>(A.GI + E1OFF, A.w1, A.b1, A.hb1, A.ha1, sm, slot);
}

// ================= phase 3a: router head, softmax, eul/task atomics =================
__global__ __launch_bounds__(256) void router_out_kernel(
    const float* __restrict__ hs, const float* __restrict__ ow, const float* __restrict__ ob,
    const int* __restrict__ tids, float* __restrict__ raw_out,
    float* __restrict__ tsum, float* __restrict__ tcnt)
{
  const int tid = threadIdx.x;
  const int lane = tid & 63, w = tid >> 6;
  const int n = blockIdx.x * 4 + w;
  float s0 = 0.f, s1 = 0.f, s2 = 0.f, s3 = 0.f;
#pragma unroll
  for (int q = 0; q < 4; ++q) {
    const int jj = lane + q * 64;
    float h = hs[(size_t)n * 256 + jj];
    h = h > 0.f ? h : 0.f;
    s0 = fmaf(h, ow[jj], s0);
    s1 = fmaf(h, ow[256 + jj], s1);
    s2 = fmaf(h, ow[512 + jj], s2);
    s3 = fmaf(h, ow[768 + jj], s3);
  }
  for (int off = 32; off; off >>= 1) {
    s0 += __shfl_xor(s0, off); s1 += __shfl_xor(s1, off);
    s2 += __shfl_xor(s2, off); s3 += __shfl_xor(s3, off);
  }
  if (lane == 0) {
    const float l0 = s0 + ob[0], l1 = s1 + ob[1], l2 = s2 + ob[2], l3 = s3 + ob[3];
    const float m = fmaxf(fmaxf(l0, l1), fmaxf(l2, l3));
    const float e0 = expf(l0 - m), e1 = expf(l1 - m), e2 = expf(l2 - m), e3 = expf(l3 - m);
    const float inv = 1.f / (e0 + e1 + e2 + e3);
    float4 rv; rv.x = e0 * inv; rv.y = e1 * inv; rv.z = e2 * inv; rv.w = e3 * inv;
    *(float4*)(raw_out + (size_t)n * 4) = rv;
    const float eul = rv.y * 128.f + rv.z * 256.f + rv.w * 512.f;
    const int tk = tids[n];
    atomicAdd(&tsum[tk], eul);
    atomicAdd(&tcnt[tk], 1.f);
  }
}

// ================= phase 3b: BN stats per column =================
__global__ __launch_bounds__(256) void bn_stats_kernel(
    const float* __restrict__ h1, const float* __restrict__ h2, const float* __restrict__ h3,
    float* __restrict__ mu, float* __restrict__ rstd)
{
  const int c = blockIdx.x;
  const float* hp; int He, hc;
  if (c < 128)      { hp = h1; He = 128; hc = c; }
  else if (c < 384) { hp = h2; He = 256; hc = c - 128; }
  else              { hp = h3; He = 512; hc = c - 384; }
  float s = 0.f, s2 = 0.f;
  for (int r = threadIdx.x; r < NTOK; r += 256) {
    const float v = hp[(size_t)r * He + hc];
    s += v; s2 = fmaf(v, v, s2);
  }
  for (int off = 32; off; off >>= 1) { s += __shfl_xor(s, off); s2 += __shfl_xor(s2, off); }
  __shared__ float red[8];
  const int lane = threadIdx.x & 63, w = threadIdx.x >> 6;
  if (lane == 0) { red[w] = s; red[4 + w] = s2; }
  __syncthreads();
  if (threadIdx.x == 0) {
    const float S = red[0] + red[1] + red[2] + red[3];
    const float S2 = red[4] + red[5] + red[6] + red[7];
    const float m = S * (1.f / 4096.f);
    float v = S2 * (1.f / 4096.f) - m * m;
    v = v > 0.f ? v : 0.f;
    mu[c] = m;
    rstd[c] = 1.f / sqrtf(v + 1e-5f);
  }
}

// ================= phase 3c: A' = gate * relu(bn(h)); plus task losses =================
__global__ __launch_bounds__(256) void aprime_kernel(
    const float* __restrict__ h1, const float* __restrict__ h2, const float* __restrict__ h3,
    const float* __restrict__ g1, const float* __restrict__ be1,
    const float* __restrict__ g2, const float* __restrict__ be2,
    const float* __restrict__ g3, const float* __restrict__ be3,
    const float* __restrict__ mu, const float* __restrict__ rstd,
    const float* __restrict__ raw, float* __restrict__ Ap,
    const float* __restrict__ tsum, const float* __restrict__ tcnt, float* __restrict__ tl_out)
{
  if (blockIdx.x == 4096) {
    if (threadIdx.x < 4) tl_out[threadIdx.x] = tsum[threadIdx.x] / tcnt[threadIdx.x];
    return;
  }
  const int n = blockIdx.x;
  for (int c = threadIdx.x; c < 896; c += 256) {
    const float* hp; const float* gg; const float* bb; int He, hc, e;
    if (c < 128)      { hp = h1; gg = g1; bb = be1; He = 128; hc = c;       e = 1; }
    else if (c < 384) { hp = h2; gg = g2; bb = be2; He = 256; hc = c - 128; e = 2; }
    else              { hp = h3; gg = g3; bb = be3; He = 512; hc = c - 384; e = 3; }
    const float h = hp[(size_t)n * He + hc];
    float v = (h - mu[c]) * rstd[c] * gg[hc] + bb[hc];
    v = v > 0.f ? v : 0.f;
    Ap[(size_t)n * 896 + c] = raw[(size_t)n * 4 + e] * v;
  }
}

// ================= phase 4: out = A' @ OWc^T + gated biases + g0*x =================
__global__ __launch_bounds__(256) void out_gemm_kernel(
    const float* __restrict__ Ap,
    const float* __restrict__ ow1, const float* __restrict__ ow2, const float* __restrict__ ow3,
    const float* __restrict__ ob1, const float* __restrict__ ob2, const float* __restrict__ ob3,
    const float* __restrict__ X, const float* __restrict__ raw, float* __restrict__ out)
{
  __shared__ float At[32*64];
  __shared__ float Bt[32*64];
  const int n0 = blockIdx.x * 64;
  const int d0 = blockIdx.y * 64;
  const int tid = threadIdx.x;
  const int lm = tid & 63, lk4 = tid >> 6;
  const int tx = tid & 15, ty = tid >> 4;
  float acc[4][4];
#pragma unroll
  for (int i = 0; i < 4; ++i)
#pragma unroll
    for (int q = 0; q < 4; ++q) acc[i][q] = 0.f;

  for (int kb = 0; kb < 896; kb += 32) {
    const float* W; int He, ko;
    if (kb < 128)      { W = ow1; He = 128; ko = 0; }
    else if (kb < 384) { W = ow2; He = 256; ko = 128; }
    else               { W = ow3; He = 512; ko = 384; }
    const float4 a0 = *(const float4*)(Ap + (size_t)(n0+lm)*896 + kb + lk4*8);
    const float4 a1 = *(const float4*)(Ap + (size_t)(n0+lm)*896 + kb + lk4*8 + 4);
    const float4 c0 = *(const float4*)(W + (size_t)(d0+lm)*He + (kb - ko) + lk4*8);
    const float4 c1 = *(const float4*)(W + (size_t)(d0+lm)*He + (kb - ko) + lk4*8 + 4);
    __syncthreads();
    At[(lk4*8+0)*64+lm]=a0.x; At[(lk4*8+1)*64+lm]=a0.y; At[(lk4*8+2)*64+lm]=a0.z; At[(lk4*8+3)*64+lm]=a0.w;
    At[(lk4*8+4)*64+lm]=a1.x; At[(lk4*8+5)*64+lm]=a1.y; At[(lk4*8+6)*64+lm]=a1.z; At[(lk4*8+7)*64+lm]=a1.w;
    Bt[(lk4*8+0)*64+lm]=c0.x; Bt[(lk4*8+1)*64+lm]=c0.y; Bt[(lk4*8+2)*64+lm]=c0.z; Bt[(lk4*8+3)*64+lm]=c0.w;
    Bt[(lk4*8+4)*64+lm]=c1.x; Bt[(lk4*8+5)*64+lm]=c1.y; Bt[(lk4*8+6)*64+lm]=c1.z; Bt[(lk4*8+7)*64+lm]=c1.w;
    __syncthreads();
#pragma unroll
    for (int k = 0; k < 32; ++k) {
      const float4 av = *(const float4*)&At[k*64 + ty*4];
      const float4 bv = *(const float4*)&Bt[k*64 + tx*4];
      acc[0][0]=fmaf(av.x,bv.x,acc[0][0]); acc[0][1]=fmaf(av.x,bv.y,acc[0][1]); acc[0][2]=fmaf(av.x,bv.z,acc[0][2]); acc[0][3]=fmaf(av.x,bv.w,acc[0][3]);
      acc[1][0]=fmaf(av.y,bv.x,acc[1][0]); acc[1][1]=fmaf(av.y,bv.y,acc[1][1]); acc[1][2]=fmaf(av.y,bv.z,acc[1][2]); acc[1][3]=fmaf(av.y,bv.w,acc[1][3]);
      acc[2][0]=fmaf(av.z,bv.x,acc[2][0]); acc[2][1]=fmaf(av.z,bv.y,acc[2][1]); acc[2][2]=fmaf(av.z,bv.z,acc[2][2]); acc[2][3]=fmaf(av.z,bv.w,acc[2][3]);
      acc[3][0]=fmaf(av.w,bv.x,acc[3][0]); acc[3][1]=fmaf(av.w,bv.y,acc[3][1]); acc[3][2]=fmaf(av.w,bv.z,acc[3][2]); acc[3][3]=fmaf(av.w,bv.w,acc[3][3]);
    }
  }
#pragma unroll
  for (int i = 0; i < 4; ++i) {
    const int n = n0 + ty * 4 + i;
    const float4 g  = *(const float4*)(raw + (size_t)n * 4);
    const float4 xv = *(const float4*)(X + (size_t)n * 512 + d0 + tx * 4);
    const float4 o1 = *(const float4*)(ob1 + d0 + tx * 4);
    const float4 o2 = *(const float4*)(ob2 + d0 + tx * 4);
    const float4 o3 = *(const float4*)(ob3 + d0 + tx * 4);
    float4 o;
    o.x = acc[i][0] + g.x*xv.x + g.y*o1.x + g.z*o2.x + g.w*o3.x;
    o.y = acc[i][1] + g.x*xv.y + g.y*o1.y + g.z*o2.y + g.w*o3.y;
    o.z = acc[i][2] + g.x*xv.z + g.y*o1.z + g.z*o2.z + g.w*o3.z;
    o.w = acc[i][3] + g.x*xv.w + g.y*o1.w + g.z*o2.w + g.w*o3.w;
    *(float4*)(out + (size_t)n * 512 + d0 + tx * 4) = o;
  }
}

// ================= host =================
extern "C" void kernel_launch(void* const* d_in, const int* in_sizes, int n_in,
                              void* d_out, int out_size, void* d_ws, size_t ws_size,
                              hipStream_t stream) {
  const float* x    = (const float*)d_in[0];
  const int*   tids = (const int*)d_in[1];
  const float* rwih = (const float*)d_in[2];
  const float* rwhh = (const float*)d_in[3];
  const float* rbih = (const float*)d_in[4];
  const float* rbhh = (const float*)d_in[5];
  const float* row  = (const float*)d_in[6];
  const float* rob  = (const float*)d_in[7];
  const float* w1ih = (const float*)d_in[8];
  const float* w1hh = (const float*)d_in[9];
  const float* b1ih = (const float*)d_in[10];
  const float* b1hh = (const float*)d_in[11];
  const float* bn1g = (const float*)d_in[12];
  const float* bn1b = (const float*)d_in[13];
  const float* ow1  = (const float*)d_in[14];
  const float* ob1  = (const float*)d_in[15];
  const float* w2ih = (const float*)d_in[16];
  const float* w2hh = (const float*)d_in[17];
  const float* b2ih = (const float*)d_in[18];
  const float* b2hh = (const float*)d_in[19];
  const float* bn2g = (const float*)d_in[20];
  const float* bn2b = (const float*)d_in[21];
  const float* ow2  = (const float*)d_in[22];
  const float* ob2  = (const float*)d_in[23];
  const float* w3ih = (const float*)d_in[24];
  const float* w3hh = (const float*)d_in[25];
  const float* b3ih = (const float*)d_in[26];
  const float* b3hh = (const float*)d_in[27];
  const float* bn3g = (const float*)d_in[28];
  const float* bn3b = (const float*)d_in[29];
  const float* ow3  = (const float*)d_in[30];
  const float* ob3  = (const float*)d_in[31];

  char* ws = (char*)d_ws;
  float* tsum = (float*)(ws + OFF_TSUM);
  float* tcnt = (float*)(ws + OFF_TCNT);
  ull*   hbR  = (ull*)(ws + OFF_HBR);
  ull*   hb3  = (ull*)(ws + OFF_HB3);
  ull*   hb2  = (ull*)(ws + OFF_HB2);
  ull*   hb1  = (ull*)(ws + OFF_HB1);
  float* GI   = (float*)(ws + OFF_GI);
  float* hs   = (float*)(ws + OFF_HS);
  float* ha3  = (float*)(ws + OFF_HA3);
  float* ha2  = (float*)(ws + OFF_HA2);
  float* ha1  = (float*)(ws + OFF_HA1);
  float* Ap   = (float*)(ws + OFF_AP);
  float* mu   = (float*)(ws + OFF_MU);
  float* rstd = (float*)(ws + OFF_RSTD);

  float* outp = (float*)d_out;
  float* rawp = outp + (size_t)NTOK * DD;        // 2,097,152
  float* tlp  = rawp + (size_t)NTOK * 4;         // +16,384

  // zero the tag/atomic region (ws is poisoned 0xAA before every launch)
  hipMemsetAsync(ws, 0, ZBYTES, stream);

  // phase 1: input projections for router + all experts
  gemm1_kernel<<<dim3(64, 54), 256, 0, stream>>>(x, rwih, w1ih, w2ih, w3ih,
                                                 rbih, b1ih, b2ih, b3ih, GI);

  // phase 2: all sequential scans concurrently (44 active WGs, spin-exchange)
  ScanArgs sa;
  sa.GI = GI; sa.rwhh = rwhh; sa.rbhh = rbhh; sa.hbR = hbR; sa.hs = hs;
  sa.w1 = w1hh; sa.b1 = b1hh; sa.hb1 = hb1; sa.ha1 = ha1;
  sa.w2 = w2hh; sa.b2 = b2hh; sa.hb2 = hb2; sa.ha2 = ha2;
  sa.w3 = w3hh; sa.b3 = b3hh; sa.hb3 = hb3; sa.ha3 = ha3;
  scan_kernel<<<dim3(128), dim3(256), 0, stream>>>(sa);

  // phase 3: router head + task-loss atomics; BN stats; A' build (+ task losses)
  router_out_kernel<<<dim3(1024), 256, 0, stream>>>(hs, row, rob, tids, rawp, tsum, tcnt);
  bn_stats_kernel<<<dim3(896), 256, 0, stream>>>(ha1, ha2, ha3, mu, rstd);
  aprime_kernel<<<dim3(4097), 256, 0, stream>>>(ha1, ha2, ha3, bn1g, bn1b, bn2g, bn2b,
                                                bn3g, bn3b, mu, rstd, rawp, Ap,
                                                tsum, tcnt, tlp);

  // phase 4: gated expert-output GEMM + identity expert + gated biases
  out_gemm_kernel<<<dim3(64, 8), 256, 0, stream>>>(Ap, ow1, ow2, ow3, ob1, ob2, ob3,
                                                   x, rawp, outp);
}

// Round 2
// 6769.167 us; speedup vs baseline: 1.2324x; 1.2324x over previous
//
#include <hip/hip_runtime.h>
#include <math.h>

// ---------------- problem constants ----------------
constexpr int TT = 256, BB = 16, DD = 512;
constexpr int NTOK = 4096;                 // T*B
constexpr int RTOT = 3456;                 // 768 + 384 + 768 + 1536
constexpr int E1OFF = 768, E2OFF = 1152, E3OFF = 1920;

// ---------------- workspace layout (bytes) ----------------
constexpr size_t OFF_TSUM = 0;                                   // 4 f
constexpr size_t OFF_TCNT = 16;                                  // 4 f
constexpr size_t OFF_CNT  = 32;                                  // 8 ints (XCD claim counters)
constexpr size_t ZBYTES   = 64;
constexpr size_t OFF_GI   = 4096;
constexpr size_t OFF_HS   = OFF_GI  + (size_t)NTOK*RTOT*4;       // router h history (poll target)
constexpr size_t OFF_HA3  = OFF_HS  + (size_t)NTOK*256*4;
constexpr size_t OFF_HA2  = OFF_HA3 + (size_t)NTOK*512*4;
constexpr size_t OFF_HA1  = OFF_HA2 + (size_t)NTOK*256*4;
constexpr size_t OFF_AP   = OFF_HA1 + (size_t)NTOK*128*4;
constexpr size_t OFF_MU   = OFF_AP  + (size_t)NTOK*896*4;
constexpr size_t OFF_RSTD = OFF_MU  + 896*4;
constexpr size_t POISON_BYTES = (size_t)NTOK*(256+512+256+128)*4;  // HS..HA1 contiguous

__device__ __forceinline__ bool is_poison(float v) {
  return __float_as_uint(v) == 0xAAAAAAAAu;
}

// ================= phase 1: gi = x @ Wih^T + b_ih (all 3456 rows) =================
__global__ __launch_bounds__(256) void gemm1_kernel(
    const float* __restrict__ X,
    const float* __restrict__ wR, const float* __restrict__ w1,
    const float* __restrict__ w2, const float* __restrict__ w3,
    const float* __restrict__ bR, const float* __restrict__ b1,
    const float* __restrict__ b2, const float* __restrict__ b3,
    float* __restrict__ GI)
{
  __shared__ float At[32*64];
  __shared__ float Bt[32*64];
  const int n0 = blockIdx.x * 64;
  const int r0 = blockIdx.y * 64;
  const float* W; const float* bias; int rs;
  if (r0 < 768)       { W = wR; bias = bR; rs = 0; }
  else if (r0 < 1152) { W = w1; bias = b1; rs = 768; }
  else if (r0 < 1920) { W = w2; bias = b2; rs = 1152; }
  else                { W = w3; bias = b3; rs = 1920; }
  const int lr0 = r0 - rs;
  const int tid = threadIdx.x;
  const int lm = tid & 63, lk4 = tid >> 6;
  const int tx = tid & 15, ty = tid >> 4;
  float acc[4][4];
#pragma unroll
  for (int i = 0; i < 4; ++i)
#pragma unroll
    for (int q = 0; q < 4; ++q) acc[i][q] = 0.f;

  for (int kb = 0; kb < 512; kb += 32) {
    const float4 a0 = *(const float4*)(X + (size_t)(n0+lm)*512 + kb + lk4*8);
    const float4 a1 = *(const float4*)(X + (size_t)(n0+lm)*512 + kb + lk4*8 + 4);
    const float4 c0 = *(const float4*)(W + (size_t)(lr0+lm)*512 + kb + lk4*8);
    const float4 c1 = *(const float4*)(W + (size_t)(lr0+lm)*512 + kb + lk4*8 + 4);
    __syncthreads();
    At[(lk4*8+0)*64+lm]=a0.x; At[(lk4*8+1)*64+lm]=a0.y; At[(lk4*8+2)*64+lm]=a0.z; At[(lk4*8+3)*64+lm]=a0.w;
    At[(lk4*8+4)*64+lm]=a1.x; At[(lk4*8+5)*64+lm]=a1.y; At[(lk4*8+6)*64+lm]=a1.z; At[(lk4*8+7)*64+lm]=a1.w;
    Bt[(lk4*8+0)*64+lm]=c0.x; Bt[(lk4*8+1)*64+lm]=c0.y; Bt[(lk4*8+2)*64+lm]=c0.z; Bt[(lk4*8+3)*64+lm]=c0.w;
    Bt[(lk4*8+4)*64+lm]=c1.x; Bt[(lk4*8+5)*64+lm]=c1.y; Bt[(lk4*8+6)*64+lm]=c1.z; Bt[(lk4*8+7)*64+lm]=c1.w;
    __syncthreads();
#pragma unroll
    for (int k = 0; k < 32; ++k) {
      const float4 av = *(const float4*)&At[k*64 + ty*4];
      const float4 bv = *(const float4*)&Bt[k*64 + tx*4];
      acc[0][0]=fmaf(av.x,bv.x,acc[0][0]); acc[0][1]=fmaf(av.x,bv.y,acc[0][1]); acc[0][2]=fmaf(av.x,bv.z,acc[0][2]); acc[0][3]=fmaf(av.x,bv.w,acc[0][3]);
      acc[1][0]=fmaf(av.y,bv.x,acc[1][0]); acc[1][1]=fmaf(av.y,bv.y,acc[1][1]); acc[1][2]=fmaf(av.y,bv.z,acc[1][2]); acc[1][3]=fmaf(av.y,bv.w,acc[1][3]);
      acc[2][0]=fmaf(av.z,bv.x,acc[2][0]); acc[2][1]=fmaf(av.z,bv.y,acc[2][1]); acc[2][2]=fmaf(av.z,bv.z,acc[2][2]); acc[2][3]=fmaf(av.z,bv.w,acc[2][3]);
      acc[3][0]=fmaf(av.w,bv.x,acc[3][0]); acc[3][1]=fmaf(av.w,bv.y,acc[3][1]); acc[3][2]=fmaf(av.w,bv.z,acc[3][2]); acc[3][3]=fmaf(av.w,bv.w,acc[3][3]);
    }
  }
  const float4 bb = *(const float4*)(bias + lr0 + tx*4);
#pragma unroll
  for (int i = 0; i < 4; ++i) {
    float4 o;
    o.x = acc[i][0] + bb.x; o.y = acc[i][1] + bb.y; o.z = acc[i][2] + bb.z; o.w = acc[i][3] + bb.w;
    *(float4*)(GI + (size_t)(n0+ty*4+i)*RTOT + r0 + tx*4) = o;
  }
}

// ================= phase 2: persistent scans (XCD-claimed roles) =================
struct ScanArgs {
  const float* GI;
  const float* rwhh; const float* rbhh; float* hs;
  const float* w1; const float* b1; float* ha1;
  const float* w2; const float* b2; float* ha2;
  const float* w3; const float* b3; float* ha3;
  int* cnt;
};

// expert scan over 4096 flat tokens. 512 threads/WG. OPW outputs per WG.
// KCN = 512/OPW lanes reduce one output; k-chunk per lane is always 32 floats.
// SINGLE (OPW==H): one WG, LDS double-buffer, no global polling.
template<int H, int OPW>
__device__ void expert_scan(const float* __restrict__ GIe, const float* __restrict__ whh,
                            const float* __restrict__ bhh, float* __restrict__ hall,
                            float* __restrict__ sm, int wg)
{
  constexpr int KCN = 512 / OPW;
  constexpr bool SINGLE = (OPW == H);
  const int tid = threadIdx.x;
  const int j = tid / KCN, kc = tid % KCN;
  const int jg = wg * OPW + j;

  float4 wr[8], wz[8], wn[8];
#pragma unroll
  for (int i4 = 0; i4 < 8; ++i4) {
    const int kk = kc * 32 + ((i4 + kc) & 7) * 4;   // bank-rotated
    wr[i4] = *(const float4*)(whh + (size_t)jg * H + kk);
    wz[i4] = *(const float4*)(whh + (size_t)(H + jg) * H + kk);
    wn[i4] = *(const float4*)(whh + (size_t)(2*H + jg) * H + kk);
  }
  float gbr = 0.f, gbz = 0.f, gbn = 0.f;
  float gr0 = 0.f, gz0 = 0.f, gn0 = 0.f, gr1 = 0.f, gz1 = 0.f, gn1 = 0.f;
  if (kc == 0) {
    gbr = bhh[jg]; gbz = bhh[H + jg]; gbn = bhh[2*H + jg];
    gr0 = GIe[jg]; gz0 = GIe[H + jg]; gn0 = GIe[2*H + jg];
    const float* g1 = GIe + RTOT;
    gr1 = g1[jg]; gz1 = g1[H + jg]; gn1 = g1[2*H + jg];
  }
  if (SINGLE) {
    if (tid < H) sm[tid] = 0.f;     // buffer 0 = h_{-1} = 0
    __syncthreads();
  }
  for (int t = 0; t < NTOK; ++t) {
    // 2-deep gi prefetch pipeline (issued before poll; ~1.5 steps of slack)
    float gr2 = 0.f, gz2 = 0.f, gn2 = 0.f;
    if (kc == 0 && t + 2 < NTOK) {
      const float* g = GIe + (size_t)(t + 2) * RTOT;
      gr2 = g[jg]; gz2 = g[H + jg]; gn2 = g[2*H + jg];
    }
    const float* hbuf;
    if (SINGLE) {
      hbuf = sm + (size_t)(t & 1) * H;
    } else {
      float val = 0.f;
      if (tid < H && t > 0) {
        const volatile float* p = (const volatile float*)(hall + (size_t)(t - 1) * H + tid);
        val = *p;
        while (is_poison(val)) val = *p;   // value IS the message (L2-local, sc0)
      }
      __syncthreads();                      // prev-step readers done with sm
      if (tid < H) sm[tid] = val;
      __syncthreads();
      hbuf = sm;
    }
    float pr = 0.f, pz = 0.f, pn = 0.f;
#pragma unroll
    for (int i4 = 0; i4 < 8; ++i4) {
      const float4 h4 = *(const float4*)(hbuf + kc * 32 + ((i4 + kc) & 7) * 4);
      pr = fmaf(wr[i4].x, h4.x, pr); pr = fmaf(wr[i4].y, h4.y, pr);
      pr = fmaf(wr[i4].z, h4.z, pr); pr = fmaf(wr[i4].w, h4.w, pr);
      pz = fmaf(wz[i4].x, h4.x, pz); pz = fmaf(wz[i4].y, h4.y, pz);
      pz = fmaf(wz[i4].z, h4.z, pz); pz = fmaf(wz[i4].w, h4.w, pz);
      pn = fmaf(wn[i4].x, h4.x, pn); pn = fmaf(wn[i4].y, h4.y, pn);
      pn = fmaf(wn[i4].z, h4.z, pn); pn = fmaf(wn[i4].w, h4.w, pn);
    }
#pragma unroll
    for (int off = KCN / 2; off; off >>= 1) {
      pr += __shfl_down(pr, off); pz += __shfl_down(pz, off); pn += __shfl_down(pn, off);
    }
    if (kc == 0) {
      const float hprev = hbuf[jg];
      const float rg = 1.f / (1.f + expf(-(gr0 + gbr + pr)));
      const float zg = 1.f / (1.f + expf(-(gz0 + gbz + pz)));
      const float nn = tanhf(gn0 + rg * (pn + gbn));
      const float hn = (1.f - zg) * nn + zg * hprev;
      if (SINGLE) {
        sm[(size_t)((t + 1) & 1) * H + jg] = hn;
        hall[(size_t)t * H + jg] = hn;
      } else {
        *(volatile float*)(hall + (size_t)t * H + jg) = hn;
      }
    }
    if (SINGLE) __syncthreads();
    gr0 = gr1; gz0 = gz1; gn0 = gn1;
    gr1 = gr2; gz1 = gz2; gn1 = gn2;
  }
}

// router scan: 8 WGs x 512. j=tid>>4 in [0,32) (32 outputs/WG), kc=tid&15 (16-chunk).
__device__ void router_scan(const float* __restrict__ GI, const float* __restrict__ whh,
                            const float* __restrict__ bhh, float* __restrict__ hs,
                            float* __restrict__ sm, int wg)
{
  float* hsmB = sm;              // 16 rows x 260 (k-major per batch row, pad 4)
  float* pbuf = sm + 16 * 260;   // 16*32*3 partials
  const int tid = threadIdx.x;
  const int j = tid >> 4, kc = tid & 15;
  const int jg = wg * 32 + j;
  float4 wr4[4], wz4[4], wn4[4];
#pragma unroll
  for (int i4 = 0; i4 < 4; ++i4) {
    const int kk = kc * 16 + ((i4 + kc) & 3) * 4;
    wr4[i4] = *(const float4*)(whh + (size_t)jg * 256 + kk);
    wz4[i4] = *(const float4*)(whh + (size_t)(256 + jg) * 256 + kk);
    wn4[i4] = *(const float4*)(whh + (size_t)(512 + jg) * 256 + kk);
  }
  const int b2 = tid >> 5, j2 = tid & 31;       // gate-stage identity
  const int jg2 = wg * 32 + j2;
  const float gbr = bhh[jg2], gbz = bhh[256 + jg2], gbn = bhh[512 + jg2];
  float gr0, gz0, gn0, gr1, gz1, gn1;
  { const float* g = GI + (size_t)b2 * RTOT;        gr0 = g[jg2]; gz0 = g[256 + jg2]; gn0 = g[512 + jg2]; }
  { const float* g = GI + (size_t)(16 + b2) * RTOT; gr1 = g[jg2]; gz1 = g[256 + jg2]; gn1 = g[512 + jg2]; }
  const int pb = tid >> 5, pk = (tid & 31) * 8;  // poll/stage identity: 8 elems/thread

  for (int t = 0; t < TT; ++t) {
    float gr2 = 0.f, gz2 = 0.f, gn2 = 0.f;
    if (t + 2 < TT) {
      const float* g = GI + (size_t)((t + 2) * 16 + b2) * RTOT;
      gr2 = g[jg2]; gz2 = g[256 + jg2]; gn2 = g[512 + jg2];
    }
    float v[8];
    if (t == 0) {
#pragma unroll
      for (int u = 0; u < 8; ++u) v[u] = 0.f;
    } else {
      const volatile float* q = (const volatile float*)(hs + (size_t)(t - 1) * 4096 + tid * 8);
#pragma unroll
      for (int u = 0; u < 8; ++u) v[u] = q[u];
      bool bad = true;
      while (bad) {
        bad = false;
#pragma unroll
        for (int u = 0; u < 8; ++u)
          if (is_poison(v[u])) { v[u] = q[u]; bad = true; }
      }
    }
    __syncthreads();               // prev readers done with hsmB
    *(float4*)(hsmB + pb * 260 + pk)     = make_float4(v[0], v[1], v[2], v[3]);
    *(float4*)(hsmB + pb * 260 + pk + 4) = make_float4(v[4], v[5], v[6], v[7]);
    __syncthreads();
    float ar[16], az[16], an[16];
#pragma unroll
    for (int b = 0; b < 16; ++b) { ar[b] = 0.f; az[b] = 0.f; an[b] = 0.f; }
#pragma unroll
    for (int i4 = 0; i4 < 4; ++i4) {
      const int col = kc * 16 + ((i4 + kc) & 3) * 4;
#pragma unroll
      for (int b = 0; b < 16; ++b) {
        const float4 h4 = *(const float4*)(hsmB + b * 260 + col);
        ar[b] = fmaf(wr4[i4].x, h4.x, ar[b]); ar[b] = fmaf(wr4[i4].y, h4.y, ar[b]);
        ar[b] = fmaf(wr4[i4].z, h4.z, ar[b]); ar[b] = fmaf(wr4[i4].w, h4.w, ar[b]);
        az[b] = fmaf(wz4[i4].x, h4.x, az[b]); az[b] = fmaf(wz4[i4].y, h4.y, az[b]);
        az[b] = fmaf(wz4[i4].z, h4.z, az[b]); az[b] = fmaf(wz4[i4].w, h4.w, az[b]);
        an[b] = fmaf(wn4[i4].x, h4.x, an[b]); an[b] = fmaf(wn4[i4].y, h4.y, an[b]);
        an[b] = fmaf(wn4[i4].z, h4.z, an[b]); an[b] = fmaf(wn4[i4].w, h4.w, an[b]);
      }
    }
#pragma unroll
    for (int off = 8; off; off >>= 1) {
#pragma unroll
      for (int b = 0; b < 16; ++b) {
        ar[b] += __shfl_down(ar[b], off);
        az[b] += __shfl_down(az[b], off);
        an[b] += __shfl_down(an[b], off);
      }
    }
    if (kc == 0) {
#pragma unroll
      for (int b = 0; b < 16; ++b) {
        pbuf[(b * 32 + j) * 3 + 0] = ar[b];
        pbuf[(b * 32 + j) * 3 + 1] = az[b];
        pbuf[(b * 32 + j) * 3 + 2] = an[b];
      }
    }
    __syncthreads();
    const float pr = pbuf[(b2 * 32 + j2) * 3 + 0];
    const float pz = pbuf[(b2 * 32 + j2) * 3 + 1];
    const float pn = pbuf[(b2 * 32 + j2) * 3 + 2];
    const float hprev = hsmB[b2 * 260 + jg2];
    const float rg = 1.f / (1.f + expf(-(gr0 + gbr + pr)));
    const float zg = 1.f / (1.f + expf(-(gz0 + gbz + pz)));
    const float nn = tanhf(gn0 + rg * (pn + gbn));
    const float hn = (1.f - zg) * nn + zg * hprev;
    *(volatile float*)(hs + (size_t)t * 4096 + b2 * 256 + jg2) = hn;
    gr0 = gr1; gz0 = gz1; gn0 = gn1;
    gr1 = gr2; gz1 = gz2; gn1 = gn2;
  }
}

__global__ __launch_bounds__(512, 1) void scan_kernel(ScanArgs A)
{
  __shared__ float sm[16 * 260 + 1536];   // router needs the max: 5696 floats
  __shared__ int role_s[2];
  if (threadIdx.x == 0) {
    unsigned x;
    asm volatile("s_getreg_b32 %0, hwreg(HW_REG_XCC_ID)" : "=s"(x));
    const int xcd = (int)(x & 7u);
    role_s[0] = xcd;
    role_s[1] = atomicAdd(A.cnt + xcd, 1);  // device-scope, claim rank within my XCD
  }
  __syncthreads();
  const int xcd = role_s[0], r = role_s[1];
  if (xcd == 0)      { if (r < 16) expert_scan<512, 32>(A.GI + E3OFF, A.w3, A.b3, A.ha3, sm, r); }
  else if (xcd == 1) { if (r < 8)  router_scan(A.GI, A.rwhh, A.rbhh, A.hs, sm, r); }
  else if (xcd == 2) { if (r < 4)  expert_scan<256, 64>(A.GI + E2OFF, A.w2, A.b2, A.ha2, sm, r); }
  else if (xcd == 3) { if (r < 1)  expert_scan<128,128>(A.GI + E1OFF, A.w1, A.b1, A.ha1, sm, r); }
  // all other WGs exit immediately (roles over-provisioned)
}

// ================= phase 3a: router head, softmax, eul/task atomics =================
__global__ __launch_bounds__(256) void router_out_kernel(
    const float* __restrict__ hs, const float* __restrict__ ow, const float* __restrict__ ob,
    const int* __restrict__ tids, float* __restrict__ raw_out,
    float* __restrict__ tsum, float* __restrict__ tcnt)
{
  const int tid = threadIdx.x;
  const int lane = tid & 63, w = tid >> 6;
  const int n = blockIdx.x * 4 + w;
  float s0 = 0.f, s1 = 0.f, s2 = 0.f, s3 = 0.f;
#pragma unroll
  for (int q = 0; q < 4; ++q) {
    const int jj = lane + q * 64;
    float h = hs[(size_t)n * 256 + jj];
    h = h > 0.f ? h : 0.f;
    s0 = fmaf(h, ow[jj], s0);
    s1 = fmaf(h, ow[256 + jj], s1);
    s2 = fmaf(h, ow[512 + jj], s2);
    s3 = fmaf(h, ow[768 + jj], s3);
  }
  for (int off = 32; off; off >>= 1) {
    s0 += __shfl_xor(s0, off); s1 += __shfl_xor(s1, off);
    s2 += __shfl_xor(s2, off); s3 += __shfl_xor(s3, off);
  }
  if (lane == 0) {
    const float l0 = s0 + ob[0], l1 = s1 + ob[1], l2 = s2 + ob[2], l3 = s3 + ob[3];
    const float m = fmaxf(fmaxf(l0, l1), fmaxf(l2, l3));
    const float e0 = expf(l0 - m), e1 = expf(l1 - m), e2 = expf(l2 - m), e3 = expf(l3 - m);
    const float inv = 1.f / (e0 + e1 + e2 + e3);
    float4 rv; rv.x = e0 * inv; rv.y = e1 * inv; rv.z = e2 * inv; rv.w = e3 * inv;
    *(float4*)(raw_out + (size_t)n * 4) = rv;
    const float eul = rv.y * 128.f + rv.z * 256.f + rv.w * 512.f;
    const int tk = tids[n];
    atomicAdd(&tsum[tk], eul);
    atomicAdd(&tcnt[tk], 1.f);
  }
}

// ================= phase 3b: BN stats per column =================
__global__ __launch_bounds__(256) void bn_stats_kernel(
    const float* __restrict__ h1, const float* __restrict__ h2, const float* __restrict__ h3,
    float* __restrict__ mu, float* __restrict__ rstd)
{
  const int c = blockIdx.x;
  const float* hp; int He, hc;
  if (c < 128)      { hp = h1; He = 128; hc = c; }
  else if (c < 384) { hp = h2; He = 256; hc = c - 128; }
  else              { hp = h3; He = 512; hc = c - 384; }
  float s = 0.f, s2 = 0.f;
  for (int r = threadIdx.x; r < NTOK; r += 256) {
    const float v = hp[(size_t)r * He + hc];
    s += v; s2 = fmaf(v, v, s2);
  }
  for (int off = 32; off; off >>= 1) { s += __shfl_xor(s, off); s2 += __shfl_xor(s2, off); }
  __shared__ float red[8];
  const int lane = threadIdx.x & 63, w = threadIdx.x >> 6;
  if (lane == 0) { red[w] = s; red[4 + w] = s2; }
  __syncthreads();
  if (threadIdx.x == 0) {
    const float S = red[0] + red[1] + red[2] + red[3];
    const float S2 = red[4] + red[5] + red[6] + red[7];
    const float m = S * (1.f / 4096.f);
    float v = S2 * (1.f / 4096.f) - m * m;
    v = v > 0.f ? v : 0.f;
    mu[c] = m;
    rstd[c] = 1.f / sqrtf(v + 1e-5f);
  }
}

// ================= phase 3c: A' = gate * relu(bn(h)); plus task losses =================
__global__ __launch_bounds__(256) void aprime_kernel(
    const float* __restrict__ h1, const float* __restrict__ h2, const float* __restrict__ h3,
    const float* __restrict__ g1, const float* __restrict__ be1,
    const float* __restrict__ g2, const float* __restrict__ be2,
    const float* __restrict__ g3, const float* __restrict__ be3,
    const float* __restrict__ mu, const float* __restrict__ rstd,
    const float* __restrict__ raw, float* __restrict__ Ap,
    const float* __restrict__ tsum, const float* __restrict__ tcnt, float* __restrict__ tl_out)
{
  if (blockIdx.x == 4096) {
    if (threadIdx.x < 4) tl_out[threadIdx.x] = tsum[threadIdx.x] / tcnt[threadIdx.x];
    return;
  }
  const int n = blockIdx.x;
  for (int c = threadIdx.x; c < 896; c += 256) {
    const float* hp; const float* gg; const float* bb; int He, hc, e;
    if (c < 128)      { hp = h1; gg = g1; bb = be1; He = 128; hc = c;       e = 1; }
    else if (c < 384) { hp = h2; gg = g2; bb = be2; He = 256; hc = c - 128; e = 2; }
    else              { hp = h3; gg = g3; bb = be3; He = 512; hc = c - 384; e = 3; }
    const float h = hp[(size_t)n * He + hc];
    float v = (h - mu[c]) * rstd[c] * gg[hc] + bb[hc];
    v = v > 0.f ? v : 0.f;
    Ap[(size_t)n * 896 + c] = raw[(size_t)n * 4 + e] * v;
  }
}

// ================= phase 4: out = A' @ OWc^T + gated biases + g0*x =================
__global__ __launch_bounds__(256) void out_gemm_kernel(
    const float* __restrict__ Ap,
    const float* __restrict__ ow1, const float* __restrict__ ow2, const float* __restrict__ ow3,
    const float* __restrict__ ob1, const float* __restrict__ ob2, const float* __restrict__ ob3,
    const float* __restrict__ X, const float* __restrict__ raw, float* __restrict__ out)
{
  __shared__ float At[32*64];
  __shared__ float Bt[32*64];
  const int n0 = blockIdx.x * 64;
  const int d0 = blockIdx.y * 64;
  const int tid = threadIdx.x;
  const int lm = tid & 63, lk4 = tid >> 6;
  const int tx = tid & 15, ty = tid >> 4;
  float acc[4][4];
#pragma unroll
  for (int i = 0; i < 4; ++i)
#pragma unroll
    for (int q = 0; q < 4; ++q) acc[i][q] = 0.f;

  for (int kb = 0; kb < 896; kb += 32) {
    const float* W; int He, ko;
    if (kb < 128)      { W = ow1; He = 128; ko = 0; }
    else if (kb < 384) { W = ow2; He = 256; ko = 128; }
    else               { W = ow3; He = 512; ko = 384; }
    const float4 a0 = *(const float4*)(Ap + (size_t)(n0+lm)*896 + kb + lk4*8);
    const float4 a1 = *(const float4*)(Ap + (size_t)(n0+lm)*896 + kb + lk4*8 + 4);
    const float4 c0 = *(const float4*)(W + (size_t)(d0+lm)*He + (kb - ko) + lk4*8);
    const float4 c1 = *(const float4*)(W + (size_t)(d0+lm)*He + (kb - ko) + lk4*8 + 4);
    __syncthreads();
    At[(lk4*8+0)*64+lm]=a0.x; At[(lk4*8+1)*64+lm]=a0.y; At[(lk4*8+2)*64+lm]=a0.z; At[(lk4*8+3)*64+lm]=a0.w;
    At[(lk4*8+4)*64+lm]=a1.x; At[(lk4*8+5)*64+lm]=a1.y; At[(lk4*8+6)*64+lm]=a1.z; At[(lk4*8+7)*64+lm]=a1.w;
    Bt[(lk4*8+0)*64+lm]=c0.x; Bt[(lk4*8+1)*64+lm]=c0.y; Bt[(lk4*8+2)*64+lm]=c0.z; Bt[(lk4*8+3)*64+lm]=c0.w;
    Bt[(lk4*8+4)*64+lm]=c1.x; Bt[(lk4*8+5)*64+lm]=c1.y; Bt[(lk4*8+6)*64+lm]=c1.z; Bt[(lk4*8+7)*64+lm]=c1.w;
    __syncthreads();
#pragma unroll
    for (int k = 0; k < 32; ++k) {
      const float4 av = *(const float4*)&At[k*64 + ty*4];
      const float4 bv = *(const float4*)&Bt[k*64 + tx*4];
      acc[0][0]=fmaf(av.x,bv.x,acc[0][0]); acc[0][1]=fmaf(av.x,bv.y,acc[0][1]); acc[0][2]=fmaf(av.x,bv.z,acc[0][2]); acc[0][3]=fmaf(av.x,bv.w,acc[0][3]);
      acc[1][0]=fmaf(av.y,bv.x,acc[1][0]); acc[1][1]=fmaf(av.y,bv.y,acc[1][1]); acc[1][2]=fmaf(av.y,bv.z,acc[1][2]); acc[1][3]=fmaf(av.y,bv.w,acc[1][3]);
      acc[2][0]=fmaf(av.z,bv.x,acc[2][0]); acc[2][1]=fmaf(av.z,bv.y,acc[2][1]); acc[2][2]=fmaf(av.z,bv.z,acc[2][2]); acc[2][3]=fmaf(av.z,bv.w,acc[2][3]);
      acc[3][0]=fmaf(av.w,bv.x,acc[3][0]); acc[3][1]=fmaf(av.w,bv.y,acc[3][1]); acc[3][2]=fmaf(av.w,bv.z,acc[3][2]); acc[3][3]=fmaf(av.w,bv.w,acc[3][3]);
    }
  }
#pragma unroll
  for (int i = 0; i < 4; ++i) {
    const int n = n0 + ty * 4 + i;
    const float4 g  = *(const float4*)(raw + (size_t)n * 4);
    const float4 xv = *(const float4*)(X + (size_t)n * 512 + d0 + tx * 4);
    const float4 o1 = *(const float4*)(ob1 + d0 + tx * 4);
    const float4 o2 = *(const float4*)(ob2 + d0 + tx * 4);
    const float4 o3 = *(const float4*)(ob3 + d0 + tx * 4);
    float4 o;
    o.x = acc[i][0] + g.x*xv.x + g.y*o1.x + g.z*o2.x + g.w*o3.x;
    o.y = acc[i][1] + g.x*xv.y + g.y*o1.y + g.z*o2.y + g.w*o3.y;
    o.z = acc[i][2] + g.x*xv.z + g.y*o1.z + g.z*o2.z + g.w*o3.z;
    o.w = acc[i][3] + g.x*xv.w + g.y*o1.w + g.z*o2.w + g.w*o3.w;
    *(float4*)(out + (size_t)n * 512 + d0 + tx * 4) = o;
  }
}

// ================= host =================
extern "C" void kernel_launch(void* const* d_in, const int* in_sizes, int n_in,
                              void* d_out, int out_size, void* d_ws, size_t ws_size,
                              hipStream_t stream) {
  const float* x    = (const float*)d_in[0];
  const int*   tids = (const int*)d_in[1];
  const float* rwih = (const float*)d_in[2];
  const float* rwhh = (const float*)d_in[3];
  const float* rbih = (const float*)d_in[4];
  const float* rbhh = (const float*)d_in[5];
  const float* row  = (const float*)d_in[6];
  const float* rob  = (const float*)d_in[7];
  const float* w1ih = (const float*)d_in[8];
  const float* w1hh = (const float*)d_in[9];
  const float* b1ih = (const float*)d_in[10];
  const float* b1hh = (const float*)d_in[11];
  const float* bn1g = (const float*)d_in[12];
  const float* bn1b = (const float*)d_in[13];
  const float* ow1  = (const float*)d_in[14];
  const float* ob1  = (const float*)d_in[15];
  const float* w2ih = (const float*)d_in[16];
  const float* w2hh = (const float*)d_in[17];
  const float* b2ih = (const float*)d_in[18];
  const float* b2hh = (const float*)d_in[19];
  const float* bn2g = (const float*)d_in[20];
  const float* bn2b = (const float*)d_in[21];
  const float* ow2  = (const float*)d_in[22];
  const float* ob2  = (const float*)d_in[23];
  const float* w3ih = (const float*)d_in[24];
  const float* w3hh = (const float*)d_in[25];
  const float* b3ih = (const float*)d_in[26];
  const float* b3hh = (const float*)d_in[27];
  const float* bn3g = (const float*)d_in[28];
  const float* bn3b = (const float*)d_in[29];
  const float* ow3  = (const float*)d_in[30];
  const float* ob3  = (const float*)d_in[31];

  char* ws = (char*)d_ws;
  float* tsum = (float*)(ws + OFF_TSUM);
  float* tcnt = (float*)(ws + OFF_TCNT);
  int*   cnt  = (int*)(ws + OFF_CNT);
  float* GI   = (float*)(ws + OFF_GI);
  float* hs   = (float*)(ws + OFF_HS);
  float* ha3  = (float*)(ws + OFF_HA3);
  float* ha2  = (float*)(ws + OFF_HA2);
  float* ha1  = (float*)(ws + OFF_HA1);
  float* Ap   = (float*)(ws + OFF_AP);
  float* mu   = (float*)(ws + OFF_MU);
  float* rstd = (float*)(ws + OFF_RSTD);

  float* outp = (float*)d_out;
  float* rawp = outp + (size_t)NTOK * DD;
  float* tlp  = rawp + (size_t)NTOK * 4;

  // zero claim counters + task accumulators; self-poison the h-history exchange
  // buffers (do NOT rely on harness poisoning — value==0xAAAAAAAA is the
  // "not ready" sentinel the scan polls against)
  hipMemsetAsync(ws, 0, ZBYTES, stream);
  hipMemsetAsync(ws + OFF_HS, 0xAA, POISON_BYTES, stream);

  // phase 1: input projections for router + all experts
  gemm1_kernel<<<dim3(64, 54), 256, 0, stream>>>(x, rwih, w1ih, w2ih, w3ih,
                                                 rbih, b1ih, b2ih, b3ih, GI);

  // phase 2: XCD-claimed persistent scans (29 role WGs; intra-XCD L2 exchange)
  ScanArgs sa;
  sa.GI = GI; sa.rwhh = rwhh; sa.rbhh = rbhh; sa.hs = hs;
  sa.w1 = w1hh; sa.b1 = b1hh; sa.ha1 = ha1;
  sa.w2 = w2hh; sa.b2 = b2hh; sa.ha2 = ha2;
  sa.w3 = w3hh; sa.b3 = b3hh; sa.ha3 = ha3;
  sa.cnt = cnt;
  scan_kernel<<<dim3(320), dim3(512), 0, stream>>>(sa);

  // phase 3: router head + task-loss atomics; BN stats; A' build (+ task losses)
  router_out_kernel<<<dim3(1024), 256, 0, stream>>>(hs, row, rob, tids, rawp, tsum, tcnt);
  bn_stats_kernel<<<dim3(896), 256, 0, stream>>>(ha1, ha2, ha3, mu, rstd);
  aprime_kernel<<<dim3(4097), 256, 0, stream>>>(ha1, ha2, ha3, bn1g, bn1b, bn2g, bn2b,
                                                bn3g, bn3b, mu, rstd, rawp, Ap,
                                                tsum, tcnt, tlp);

  // phase 4: gated expert-output GEMM + identity expert + gated biases
  out_gemm_kernel<<<dim3(64, 8), 256, 0, stream>>>(Ap, ow1, ow2, ow3, ob1, ob2, ob3,
                                                   x, rawp, outp);
}